// Round 11
// baseline (1974.654 us; speedup 1.0000x reference)
//
#include <hip/hip_runtime.h>
#include <stdint.h>
#include <stddef.h>

#define NTOK 8192
#define DDIM 1024
#define NEXP 8
#define HDIM 2048
#define LSTRIDE (NTOK + 256)
#define NCHUNK 128                      /* 64 tokens per chunk */
#define MAXROWS (2 * NTOK + NEXP * 256) /* 18432 compacted rows, 256-padded */

typedef __attribute__((ext_vector_type(4))) float f32x4;
typedef __attribute__((ext_vector_type(8))) short s16x8;
typedef __attribute__((ext_vector_type(4))) short s16x4;

static __device__ __forceinline__ unsigned short f2bf(float f) {
  union { float f; unsigned u; } v; v.f = f;
  unsigned r = v.u + 0x7FFFu + ((v.u >> 16) & 1u); // RNE
  return (unsigned short)(r >> 16);
}
static __device__ __forceinline__ float bf2f(unsigned short h) {
  union { unsigned u; float f; } v; v.u = ((unsigned)h) << 16;
  return v.f;
}

static __device__ __forceinline__ void gll16(const void* g, void* l) {
  __builtin_amdgcn_global_load_lds((const __attribute__((address_space(1))) void*)g,
                                   (__attribute__((address_space(3))) void*)l, 16, 0, 0);
}

#define BAR_END() do { __builtin_amdgcn_s_barrier(); __builtin_amdgcn_sched_barrier(0); } while (0)
#define VMW0() asm volatile("s_waitcnt vmcnt(0)" ::: "memory")

__global__ void k_sentinel(float* out) { if (threadIdx.x == 0) out[0] = 1.0e6f; }

// ---- rowbase helper: rowb(e) = sum of 256-aligned counts below e ----
static __device__ __forceinline__ int rowbase(const int* __restrict__ ctrl, int e) {
  int rowb = 0;
#pragma unroll
  for (int q = 0; q < NEXP; ++q) if (q < e) rowb += (ctrl[q] + 255) & ~255;
  return rowb;
}

// ---- fused prep: blocks [0,2048) = router (+x cvt); blocks [2048,3072) = wg/wi cvt ----
__global__ __launch_bounds__(256) void k_prep(const float* __restrict__ x,
    const float* __restrict__ gw,
    const float* __restrict__ wgate, const float* __restrict__ win,
    unsigned short* __restrict__ wgb, unsigned short* __restrict__ wib,
    unsigned* __restrict__ tokE, float2* __restrict__ tokW2, unsigned short* __restrict__ xbf) {
  int b = blockIdx.x;
  if (b >= 2048) {
    const float* srcs[2] = { wgate, win };
    unsigned short* dsts[2] = { wgb, wib };
    int g = (b - 2048) * 256 + threadIdx.x;
    const int stride = 1024 * 256;
#pragma unroll
    for (int it = 0; it < 16; ++it) {
      int arr = g >> 21;
      int idx = g & ((1 << 21) - 1);
      const f32x4* s = (const f32x4*)(srcs[arr] + (size_t)idx * 8);
      f32x4 a = s[0], c = s[1];
      s16x8 o;
      o[0] = f2bf(a[0]); o[1] = f2bf(a[1]); o[2] = f2bf(a[2]); o[3] = f2bf(a[3]);
      o[4] = f2bf(c[0]); o[5] = f2bf(c[1]); o[6] = f2bf(c[2]); o[7] = f2bf(c[3]);
      *(s16x8*)(dsts[arr] + (size_t)idx * 8) = o;
      g += stride;
    }
    return;
  }
  int lane = threadIdx.x & 63;
  int t = b * 4 + (threadIdx.x >> 6);
  const f32x4* x4 = (const f32x4*)x;
  const f32x4* g4 = (const f32x4*)gw;
  f32x4 xr[4];
#pragma unroll
  for (int j = 0; j < 4; ++j) xr[j] = x4[(size_t)t * 256 + j * 64 + lane];
#pragma unroll
  for (int j = 0; j < 4; ++j) {
    s16x4 o;
    o[0] = f2bf(xr[j][0]); o[1] = f2bf(xr[j][1]); o[2] = f2bf(xr[j][2]); o[3] = f2bf(xr[j][3]);
    *(s16x4*)(xbf + (size_t)t * DDIM + (j * 64 + lane) * 4) = o;
  }
  float le[8];
#pragma unroll
  for (int e = 0; e < 8; ++e) {
    float p = 0.f;
#pragma unroll
    for (int j = 0; j < 4; ++j) {
      f32x4 g = g4[e * 256 + j * 64 + lane];
      p += xr[j][0] * g[0] + xr[j][1] * g[1] + xr[j][2] * g[2] + xr[j][3] * g[3];
    }
#pragma unroll
    for (int off = 32; off > 0; off >>= 1) p += __shfl_xor(p, off, 64);
    le[e] = p;
  }
  if (lane == 0) {
    int i0 = 0; float v0 = le[0];
#pragma unroll
    for (int e = 1; e < 8; ++e) if (le[e] > v0) { v0 = le[e]; i0 = e; }
    int i1 = -1; float v1 = 0.f;
#pragma unroll
    for (int e = 0; e < 8; ++e) if (e != i0 && (i1 < 0 || le[e] > v1)) { v1 = le[e]; i1 = e; }
    float bb = __expf(v1 - v0);
    float s = 1.f + bb;
    tokE[t] = (unsigned)i0 | ((unsigned)i1 << 8);
    tokW2[t] = make_float2(1.f / s, bb / s);
  }
}

// ---- merged sort: each of 128 blocks scans all tokE (32 KB, L2-hot),
//      builds the full per-chunk histogram in LDS, derives its own chunk's
//      per-expert global bases, then scatters its 64 tokens. ----
__global__ __launch_bounds__(64) void k_sort(const unsigned* __restrict__ tokE,
    const float2* __restrict__ tokW2, int* __restrict__ ctrl,
    int* __restrict__ listTok, float* __restrict__ listW, int* __restrict__ listSlot) {
  __shared__ int cnts[NCHUNK][NEXP];   // 4 KB
  __shared__ int base8[NEXP];
  __shared__ int lcnt[NEXP];
  int c = blockIdx.x, tid = threadIdx.x;
#pragma unroll
  for (int k = 0; k < 16; ++k) ((int*)cnts)[tid + k * 64] = 0;
  if (tid < NEXP) lcnt[tid] = 0;
  __syncthreads();
#pragma unroll
  for (int k = 0; k < 2; ++k) {
    int ch = tid * 2 + k;
    const unsigned* p = tokE + ch * 64;
#pragma unroll 8
    for (int i = 0; i < 64; ++i) {
      unsigned v = p[i];
      atomicAdd(&cnts[ch][v & 255], 1);
      atomicAdd(&cnts[ch][(v >> 8) & 255], 1);
    }
  }
  __syncthreads();
  if (tid < NEXP) {
    int run = 0, base = 0;
    for (int q = 0; q < NCHUNK; ++q) {
      if (q == c) base = run;
      run += cnts[q][tid];
    }
    base8[tid] = base;
    if (c == 0) ctrl[tid] = run;
  }
  __syncthreads();
  int t = c * 64 + tid;
  unsigned v = tokE[t];
  int e0 = v & 255, e1 = (v >> 8) & 255;
  float2 w = tokW2[t];
  int l0 = atomicAdd(&lcnt[e0], 1);
  int l1 = atomicAdd(&lcnt[e1], 1);
  int i0 = base8[e0] + l0;
  int i1 = base8[e1] + l1;
  listTok[e0 * LSTRIDE + i0] = t; listW[e0 * LSTRIDE + i0] = w.x; listSlot[e0 * LSTRIDE + i0] = 0;
  listTok[e1 * LSTRIDE + i1] = t; listW[e1 * LSTRIDE + i1] = w.y; listSlot[e1 * LSTRIDE + i1] = 1;
}

// =====================================================================
// GEMM1: h = silu(Xg @ Wg^T) * (Xg @ Wi^T)
// 2-phase single-buffer (64 KB LDS) x 2 blocks/CU: stage -> vmcnt0+bar
// -> ds_read + 64 MFMA -> bar. Inter-block overlap hides stage latency
// (m114: co-resident blocks overlap MFMA and VMEM fully).
// blockIdx.z==8 -> 512 role-split blocks convert wout (fp32->bf16).
// =====================================================================
__global__ __launch_bounds__(512, 4) void k_gemm1(const unsigned short* __restrict__ xbf,
    const unsigned short* __restrict__ wg, const unsigned short* __restrict__ wi,
    const int* __restrict__ ctrl, const int* __restrict__ listTok,
    unsigned short* __restrict__ hbuf,
    const float* __restrict__ wout, unsigned short* __restrict__ wob) {
  int e = blockIdx.z;
  if (e == 8) {
    int g = (blockIdx.x + blockIdx.y * 16) * 512 + threadIdx.x;
    const int stride = 512 * 512;
#pragma unroll
    for (int it = 0; it < 8; ++it) {
      const f32x4* s = (const f32x4*)(wout + (size_t)g * 8);
      f32x4 a = s[0], c = s[1];
      s16x8 o;
      o[0] = f2bf(a[0]); o[1] = f2bf(a[1]); o[2] = f2bf(a[2]); o[3] = f2bf(a[3]);
      o[4] = f2bf(c[0]); o[5] = f2bf(c[1]); o[6] = f2bf(c[2]); o[7] = f2bf(c[3]);
      *(s16x8*)(wob + (size_t)g * 8) = o;
      g += stride;
    }
    return;
  }
  int cnt = ctrl[e];
  int m0 = blockIdx.y * 256;
  if (m0 >= cnt) return;
  int rowb = rowbase(ctrl, e);
  int n0 = blockIdx.x * 128;

  __shared__ __align__(16) char lds[65536];   // Bg[0,16K) Bi[16K,32K) A[32K,64K)
  char* ldsc = &lds[0];

  int tid = threadIdx.x, lane = tid & 63, wv = tid >> 6;
  int wm = wv >> 1, wn = wv & 1;

  int srow = tid >> 3;
  int scol = (((tid & 7) ^ ((tid >> 3) & 7)) << 4);  // inverse-swizzled source col byte
  int sdst = wv << 10;                               // wave-uniform LDS dest
  const char* pA[2][2];
  const char* pBg[2];
  const char* pBi[2];
#pragma unroll
  for (int rg = 0; rg < 2; ++rg)
#pragma unroll
    for (int sb = 0; sb < 2; ++sb) {
      int idx = m0 + rg * 128 + sb * 64 + srow;
      if (idx >= cnt) idx = cnt - 1;                 // pad rows: clamp (cnt>=1 here)
      int tok = listTok[e * LSTRIDE + idx];
      pA[rg][sb] = (const char*)xbf + (size_t)tok * 2048 + scol;
    }
#pragma unroll
  for (int sb = 0; sb < 2; ++sb) {
    pBg[sb] = (const char*)wg + ((size_t)e * HDIM + n0 + sb * 64 + srow) * 2048 + scol;
    pBi[sb] = (const char*)wi + ((size_t)e * HDIM + n0 + sb * 64 + srow) * 2048 + scol;
  }

  int rowB = (lane & 15) << 7;
  int mk = (lane & 7) << 4;
  int q16 = (lane >> 4) << 4;
  int c0 = q16 ^ mk, c1 = (q16 + 64) ^ mk;
  int aO0 = 32768 + (wm >> 1) * 16384 + ((wm & 1) * 64) * 128 + rowB + c0;
  int aO1 = aO0 - c0 + c1;
  int gO0 = (wn * 64) * 128 + rowB + c0;
  int gO1 = gO0 - c0 + c1;
  int iO0 = 16384 + (wn * 64) * 128 + rowB + c0;
  int iO1 = iO0 - c0 + c1;

#define G1_STA(RG, KO) do { \
    gll16(pA[RG][0] + (KO), ldsc + 32768 + (RG) * 16384 + sdst); \
    gll16(pA[RG][1] + (KO), ldsc + 32768 + (RG) * 16384 + 8192 + sdst); } while (0)
#define G1_STG(KO) do { \
    gll16(pBg[0] + (KO), ldsc + sdst); \
    gll16(pBg[1] + (KO), ldsc + 8192 + sdst); } while (0)
#define G1_STI(KO) do { \
    gll16(pBi[0] + (KO), ldsc + 16384 + sdst); \
    gll16(pBi[1] + (KO), ldsc + 16384 + 8192 + sdst); } while (0)
#define G1_RDA() { _Pragma("unroll") for (int mf = 0; mf < 4; ++mf) { \
    af[mf][0] = *(const s16x8*)(ldsc + aO0 + mf * 2048); \
    af[mf][1] = *(const s16x8*)(ldsc + aO1 + mf * 2048); } }
#define G1_RDG() { _Pragma("unroll") for (int nf = 0; nf < 4; ++nf) { \
    bg[nf][0] = *(const s16x8*)(ldsc + gO0 + nf * 2048); \
    bg[nf][1] = *(const s16x8*)(ldsc + gO1 + nf * 2048); } }
#define G1_RDI() { _Pragma("unroll") for (int nf = 0; nf < 4; ++nf) { \
    bi[nf][0] = *(const s16x8*)(ldsc + iO0 + nf * 2048); \
    bi[nf][1] = *(const s16x8*)(ldsc + iO1 + nf * 2048); } }
#define G1_MMG(NH) do { __builtin_amdgcn_s_setprio(1); \
    _Pragma("unroll") for (int mf = 0; mf < 4; ++mf) _Pragma("unroll") for (int nf = 0; nf < 2; ++nf) { \
      accg[mf][(NH)*2+nf] = __builtin_amdgcn_mfma_f32_16x16x32_bf16(af[mf][0], bg[(NH)*2+nf][0], accg[mf][(NH)*2+nf], 0, 0, 0); \
      accg[mf][(NH)*2+nf] = __builtin_amdgcn_mfma_f32_16x16x32_bf16(af[mf][1], bg[(NH)*2+nf][1], accg[mf][(NH)*2+nf], 0, 0, 0); } \
    __builtin_amdgcn_s_setprio(0); } while (0)
#define G1_MMI(NH) do { __builtin_amdgcn_s_setprio(1); \
    _Pragma("unroll") for (int mf = 0; mf < 4; ++mf) _Pragma("unroll") for (int nf = 0; nf < 2; ++nf) { \
      acci[mf][(NH)*2+nf] = __builtin_amdgcn_mfma_f32_16x16x32_bf16(af[mf][0], bi[(NH)*2+nf][0], acci[mf][(NH)*2+nf], 0, 0, 0); \
      acci[mf][(NH)*2+nf] = __builtin_amdgcn_mfma_f32_16x16x32_bf16(af[mf][1], bi[(NH)*2+nf][1], acci[mf][(NH)*2+nf], 0, 0, 0); } \
    __builtin_amdgcn_s_setprio(0); } while (0)

  f32x4 accg[4][4], acci[4][4];
#pragma unroll
  for (int a = 0; a < 4; ++a)
#pragma unroll
    for (int b = 0; b < 4; ++b) { accg[a][b] = (f32x4){0.f,0.f,0.f,0.f}; acci[a][b] = (f32x4){0.f,0.f,0.f,0.f}; }
  s16x8 af[4][2], bg[4][2], bi[4][2];

  const int NIT = DDIM / 64;   // 16 K-tiles
#pragma unroll
  for (int kt = 0; kt < NIT; ++kt) {
    const int ko = kt * 128;   // byte offset, max 1920 -> folds into imm
    G1_STG(ko); G1_STA(0, ko); G1_STI(ko); G1_STA(1, ko);
    VMW0();
    BAR_END();                 // all waves' loads landed -> tile complete
    G1_RDA(); G1_RDG(); G1_RDI();
    G1_MMG(0); G1_MMG(1); G1_MMI(0); G1_MMI(1);
    BAR_END();                 // all waves done reading before next stage
  }

#pragma unroll
  for (int mf = 0; mf < 4; ++mf)
#pragma unroll
    for (int j = 0; j < 4; ++j) {
      int r = wm * 64 + mf * 16 + ((lane >> 4) << 2) + j;
      size_t rowoff = (size_t)(rowb + m0 + r) * HDIM;
#pragma unroll
      for (int nf = 0; nf < 4; ++nf) {
        int cc = n0 + wn * 64 + nf * 16 + (lane & 15);
        float g = accg[mf][nf][j];
        float iv = acci[mf][nf][j];
        float hv = g / (1.f + __expf(-g)) * iv;
        hbuf[rowoff + cc] = f2bf(hv);
      }
    }
#undef G1_STA
#undef G1_STG
#undef G1_STI
#undef G1_RDA
#undef G1_RDG
#undef G1_RDI
#undef G1_MMG
#undef G1_MMI
}

// =====================================================================
// GEMM2: y[slot][token] = w * (h @ Wo^T)
// 2-phase single-buffer (48 KB LDS) x 2 blocks/CU (VGPR-capped), BM=256,
// BN=128, BK=64, 8 waves (4M x 2N), 16x16x32 MFMA.
// =====================================================================
__global__ __launch_bounds__(512, 4) void k_gemm2(const unsigned short* __restrict__ hbuf,
    const unsigned short* __restrict__ wo, const int* __restrict__ ctrl,
    const int* __restrict__ listTok, const float* __restrict__ listW,
    const int* __restrict__ listSlot, unsigned short* __restrict__ ybuf) {
  int e = blockIdx.z;
  int cnt = ctrl[e];
  int m0 = blockIdx.y * 256;
  if (m0 >= cnt) return;
  int rowb = rowbase(ctrl, e);
  int n0 = blockIdx.x * 128;

  __shared__ __align__(16) char lds[49152];   // A[0,32K) B[32K,48K)
  char* ldsc = &lds[0];

  int tid = threadIdx.x, lane = tid & 63, wv = tid >> 6;
  int wm = wv >> 1, wn = wv & 1;

  int srow = tid >> 3;
  int scol = (((tid & 7) ^ ((tid >> 3) & 7)) << 4);
  int sdst = wv << 10;
  const char* pA[2][2];
  const char* pB[2];
#pragma unroll
  for (int rg = 0; rg < 2; ++rg)
#pragma unroll
    for (int sb = 0; sb < 2; ++sb)
      pA[rg][sb] = (const char*)hbuf + (size_t)(rowb + m0 + rg * 128 + sb * 64 + srow) * 4096 + scol;
#pragma unroll
  for (int sb = 0; sb < 2; ++sb)
    pB[sb] = (const char*)wo + ((size_t)e * DDIM + n0 + sb * 64 + srow) * 4096 + scol;

  int rowB = (lane & 15) << 7;
  int mk = (lane & 7) << 4;
  int q16 = (lane >> 4) << 4;
  int c0 = q16 ^ mk, c1 = (q16 + 64) ^ mk;
  int aO0 = wm * 8192 + rowB + c0;
  int aO1 = aO0 - c0 + c1;
  int bO0 = 32768 + wn * 8192 + rowB + c0;
  int bO1 = bO0 - c0 + c1;

#define G2_STA(RG, KO) do { \
    gll16(pA[RG][0] + (KO), ldsc + (RG) * 16384 + sdst); \
    gll16(pA[RG][1] + (KO), ldsc + (RG) * 16384 + 8192 + sdst); } while (0)
#define G2_STB(KO) do { \
    gll16(pB[0] + (KO), ldsc + 32768 + sdst); \
    gll16(pB[1] + (KO), ldsc + 32768 + 8192 + sdst); } while (0)
#define G2_RDA() { _Pragma("unroll") for (int mf = 0; mf < 4; ++mf) { \
    af[mf][0] = *(const s16x8*)(ldsc + aO0 + mf * 2048); \
    af[mf][1] = *(const s16x8*)(ldsc + aO1 + mf * 2048); } }
#define G2_RDB() { _Pragma("unroll") for (int nf = 0; nf < 4; ++nf) { \
    bf[nf][0] = *(const s16x8*)(ldsc + bO0 + nf * 2048); \
    bf[nf][1] = *(const s16x8*)(ldsc + bO1 + nf * 2048); } }
#define G2_MM(NH) do { __builtin_amdgcn_s_setprio(1); \
    _Pragma("unroll") for (int mf = 0; mf < 4; ++mf) _Pragma("unroll") for (int nf = 0; nf < 2; ++nf) { \
      acc[mf][(NH)*2+nf] = __builtin_amdgcn_mfma_f32_16x16x32_bf16(af[mf][0], bf[(NH)*2+nf][0], acc[mf][(NH)*2+nf], 0, 0, 0); \
      acc[mf][(NH)*2+nf] = __builtin_amdgcn_mfma_f32_16x16x32_bf16(af[mf][1], bf[(NH)*2+nf][1], acc[mf][(NH)*2+nf], 0, 0, 0); } \
    __builtin_amdgcn_s_setprio(0); } while (0)

  f32x4 acc[4][4];
#pragma unroll
  for (int a = 0; a < 4; ++a)
#pragma unroll
    for (int b = 0; b < 4; ++b) acc[a][b] = (f32x4){0.f,0.f,0.f,0.f};
  s16x8 af[4][2], bf[4][2];

  const int NIT = HDIM / 64;   // 32 K-tiles
#pragma unroll
  for (int kt = 0; kt < NIT; ++kt) {
    const int ko = kt * 128;   // max 3968 < 4096 -> folds into imm
    G2_STA(0, ko); G2_STA(1, ko); G2_STB(ko);
    VMW0();
    BAR_END();
    G2_RDA(); G2_RDB();
    G2_MM(0); G2_MM(1);
    BAR_END();
  }

#pragma unroll
  for (int mf = 0; mf < 4; ++mf)
#pragma unroll
    for (int j = 0; j < 4; ++j) {
      int r = wm * 64 + mf * 16 + ((lane >> 4) << 2) + j;
      int mrow = m0 + r;
      if (mrow < cnt) {
        int tok = listTok[e * LSTRIDE + mrow];
        float wgt = listW[e * LSTRIDE + mrow];
        int slot = listSlot[e * LSTRIDE + mrow];
        size_t base = ((size_t)slot * NTOK + tok) * DDIM + n0 + wn * 64;
#pragma unroll
        for (int nf = 0; nf < 4; ++nf)
          ybuf[base + nf * 16 + (lane & 15)] = f2bf(acc[mf][nf][j] * wgt);
      }
    }
#undef G2_STA
#undef G2_STB
#undef G2_RDA
#undef G2_RDB
#undef G2_MM
}

// ---- reduce: out = y0 + y1 (fp32 out), vectorized ----
__global__ __launch_bounds__(256) void k_reduce(const unsigned short* __restrict__ ybuf,
                                                float* __restrict__ out, int n8) {
  int i = blockIdx.x * blockDim.x + threadIdx.x;
  int stride = gridDim.x * blockDim.x;
  const unsigned short* y0 = ybuf;
  const unsigned short* y1 = ybuf + (size_t)NTOK * DDIM;
  for (; i < n8; i += stride) {
    s16x8 a = *(const s16x8*)(y0 + (size_t)i * 8);
    s16x8 b = *(const s16x8*)(y1 + (size_t)i * 8);
    f32x4 o0, o1;
#pragma unroll
    for (int j = 0; j < 4; ++j) o0[j] = bf2f((unsigned short)a[j]) + bf2f((unsigned short)b[j]);
#pragma unroll
    for (int j = 0; j < 4; ++j) o1[j] = bf2f((unsigned short)a[4 + j]) + bf2f((unsigned short)b[4 + j]);
    f32x4* d = (f32x4*)(out + (size_t)i * 8);
    d[0] = o0; d[1] = o1;
  }
}

extern "C" void kernel_launch(void* const* d_in, const int* in_sizes, int n_in,
                              void* d_out, int out_size, void* d_ws, size_t ws_size,
                              hipStream_t stream) {
  const float* x     = (const float*)d_in[0];
  const float* gw    = (const float*)d_in[1];
  const float* wgate = (const float*)d_in[2];
  const float* win   = (const float*)d_in[3];
  const float* wout  = (const float*)d_in[4];
  float* out = (float*)d_out;

  const size_t LBYTES     = (size_t)NEXP * LSTRIDE * 4;
  const size_t OFF_LIST   = 256;
  const size_t OFF_LISTW  = OFF_LIST + LBYTES;
  const size_t OFF_SLOT   = OFF_LISTW + LBYTES;
  const size_t OFF_TE     = OFF_SLOT + LBYTES;          // tokE: NTOK u32
  const size_t OFF_TW     = OFF_TE + (size_t)NTOK * 4;  // tokW2: NTOK float2
  const size_t OFF_XBF = (size_t)1 << 20;
  const size_t OFF_WG  = OFF_XBF + (size_t)NTOK * DDIM * 2;
  const size_t OFF_WI  = OFF_WG + (size_t)NEXP * HDIM * DDIM * 2;
  const size_t OFF_WO  = OFF_WI + (size_t)NEXP * HDIM * DDIM * 2;
  const size_t OFF_H   = OFF_WO + (size_t)NEXP * DDIM * HDIM * 2;
  const size_t OFF_Y   = OFF_WG;                        // ybuf aliases wgb (dead after gemm1)
  const size_t TOTAL   = OFF_H + (size_t)MAXROWS * HDIM * 2;

  if (ws_size < TOTAL) { k_sentinel<<<1, 64, 0, stream>>>(out); return; }

  char* ws = (char*)d_ws;
  int* ctrl            = (int*)ws;                      // [0..7]=cnt
  int* listTok         = (int*)(ws + OFF_LIST);
  float* listW         = (float*)(ws + OFF_LISTW);
  int* listSlot        = (int*)(ws + OFF_SLOT);
  unsigned* tokE       = (unsigned*)(ws + OFF_TE);
  float2* tokW2        = (float2*)(ws + OFF_TW);
  unsigned short* xbf  = (unsigned short*)(ws + OFF_XBF);
  unsigned short* wgb  = (unsigned short*)(ws + OFF_WG);
  unsigned short* wib  = (unsigned short*)(ws + OFF_WI);
  unsigned short* wob  = (unsigned short*)(ws + OFF_WO);
  unsigned short* hbuf = (unsigned short*)(ws + OFF_H);
  unsigned short* ybuf = (unsigned short*)(ws + OFF_Y);

  k_prep<<<3072, 256, 0, stream>>>(x, gw, wgate, win, wgb, wib, tokE, tokW2, xbf);
  k_sort<<<NCHUNK, 64, 0, stream>>>(tokE, tokW2, ctrl, listTok, listW, listSlot);

  k_gemm1<<<dim3(HDIM / 128, NTOK / 256, NEXP + 1), 512, 0, stream>>>(xbf, wgb, wib, ctrl, listTok, hbuf, wout, wob);
  k_gemm2<<<dim3(DDIM / 128, NTOK / 256, NEXP), 512, 0, stream>>>(hbuf, wob, ctrl, listTok, listW, listSlot, ybuf);
  k_reduce<<<512, 256, 0, stream>>>(ybuf, out, NTOK * DDIM / 8);
}

// Round 12
// 346.142 us; speedup vs baseline: 5.7048x; 5.7048x over previous
//
#include <hip/hip_runtime.h>
#include <stdint.h>
#include <stddef.h>

#define NTOK 8192
#define DDIM 1024
#define NEXP 8
#define HDIM 2048
#define LSTRIDE (NTOK + 256)
#define NCHUNK 128                      /* 64 tokens per chunk */
#define MAXROWS (2 * NTOK + NEXP * 256) /* 18432 compacted rows, 256-padded */

typedef __attribute__((ext_vector_type(4))) float f32x4;
typedef __attribute__((ext_vector_type(8))) short s16x8;
typedef __attribute__((ext_vector_type(4))) short s16x4;

static __device__ __forceinline__ unsigned short f2bf(float f) {
  union { float f; unsigned u; } v; v.f = f;
  unsigned r = v.u + 0x7FFFu + ((v.u >> 16) & 1u); // RNE
  return (unsigned short)(r >> 16);
}
static __device__ __forceinline__ float bf2f(unsigned short h) {
  union { unsigned u; float f; } v; v.u = ((unsigned)h) << 16;
  return v.f;
}

static __device__ __forceinline__ void gll16(const void* g, void* l) {
  __builtin_amdgcn_global_load_lds((const __attribute__((address_space(1))) void*)g,
                                   (__attribute__((address_space(3))) void*)l, 16, 0, 0);
}

#define BAR_MID() __builtin_amdgcn_s_barrier()
#define BAR_END() do { __builtin_amdgcn_s_barrier(); __builtin_amdgcn_sched_barrier(0); } while (0)
#define VMW6() asm volatile("s_waitcnt vmcnt(6)" ::: "memory")
#define VMW0() asm volatile("s_waitcnt vmcnt(0)" ::: "memory")

__global__ void k_sentinel(float* out) { if (threadIdx.x == 0) out[0] = 1.0e6f; }

// ---- rowbase helper: rowb(e) = sum of 256-aligned counts below e ----
static __device__ __forceinline__ int rowbase(const int* __restrict__ ctrl, int e) {
  int rowb = 0;
#pragma unroll
  for (int q = 0; q < NEXP; ++q) if (q < e) rowb += (ctrl[q] + 255) & ~255;
  return rowb;
}

// ---- fused prep: blocks [0,2048) = router (+x cvt); blocks [2048,3072) = wg/wi cvt ----
__global__ __launch_bounds__(256) void k_prep(const float* __restrict__ x,
    const float* __restrict__ gw,
    const float* __restrict__ wgate, const float* __restrict__ win,
    unsigned short* __restrict__ wgb, unsigned short* __restrict__ wib,
    unsigned* __restrict__ tokE, float2* __restrict__ tokW2, unsigned short* __restrict__ xbf) {
  int b = blockIdx.x;
  if (b >= 2048) {
    const float* srcs[2] = { wgate, win };
    unsigned short* dsts[2] = { wgb, wib };
    int g = (b - 2048) * 256 + threadIdx.x;
    const int stride = 1024 * 256;
#pragma unroll
    for (int it = 0; it < 16; ++it) {
      int arr = g >> 21;
      int idx = g & ((1 << 21) - 1);
      const f32x4* s = (const f32x4*)(srcs[arr] + (size_t)idx * 8);
      f32x4 a = s[0], c = s[1];
      s16x8 o;
      o[0] = f2bf(a[0]); o[1] = f2bf(a[1]); o[2] = f2bf(a[2]); o[3] = f2bf(a[3]);
      o[4] = f2bf(c[0]); o[5] = f2bf(c[1]); o[6] = f2bf(c[2]); o[7] = f2bf(c[3]);
      *(s16x8*)(dsts[arr] + (size_t)idx * 8) = o;
      g += stride;
    }
    return;
  }
  int lane = threadIdx.x & 63;
  int t = b * 4 + (threadIdx.x >> 6);
  const f32x4* x4 = (const f32x4*)x;
  const f32x4* g4 = (const f32x4*)gw;
  f32x4 xr[4];
#pragma unroll
  for (int j = 0; j < 4; ++j) xr[j] = x4[(size_t)t * 256 + j * 64 + lane];
#pragma unroll
  for (int j = 0; j < 4; ++j) {
    s16x4 o;
    o[0] = f2bf(xr[j][0]); o[1] = f2bf(xr[j][1]); o[2] = f2bf(xr[j][2]); o[3] = f2bf(xr[j][3]);
    *(s16x4*)(xbf + (size_t)t * DDIM + (j * 64 + lane) * 4) = o;
  }
  float le[8];
#pragma unroll
  for (int e = 0; e < 8; ++e) {
    float p = 0.f;
#pragma unroll
    for (int j = 0; j < 4; ++j) {
      f32x4 g = g4[e * 256 + j * 64 + lane];
      p += xr[j][0] * g[0] + xr[j][1] * g[1] + xr[j][2] * g[2] + xr[j][3] * g[3];
    }
#pragma unroll
    for (int off = 32; off > 0; off >>= 1) p += __shfl_xor(p, off, 64);
    le[e] = p;
  }
  if (lane == 0) {
    int i0 = 0; float v0 = le[0];
#pragma unroll
    for (int e = 1; e < 8; ++e) if (le[e] > v0) { v0 = le[e]; i0 = e; }
    int i1 = -1; float v1 = 0.f;
#pragma unroll
    for (int e = 0; e < 8; ++e) if (e != i0 && (i1 < 0 || le[e] > v1)) { v1 = le[e]; i1 = e; }
    float bb = __expf(v1 - v0);
    float s = 1.f + bb;
    tokE[t] = (unsigned)i0 | ((unsigned)i1 << 8);
    tokW2[t] = make_float2(1.f / s, bb / s);
  }
}

// ---- merged sort: each of 128 blocks scans all tokE (32 KB, L2-hot),
//      builds the full per-chunk histogram in LDS, derives its own chunk's
//      per-expert global bases, then scatters its 64 tokens. ----
__global__ __launch_bounds__(64) void k_sort(const unsigned* __restrict__ tokE,
    const float2* __restrict__ tokW2, int* __restrict__ ctrl,
    int* __restrict__ listTok, float* __restrict__ listW, int* __restrict__ listSlot) {
  __shared__ int cnts[NCHUNK][NEXP];   // 4 KB
  __shared__ int base8[NEXP];
  __shared__ int lcnt[NEXP];
  int c = blockIdx.x, tid = threadIdx.x;
#pragma unroll
  for (int k = 0; k < 16; ++k) ((int*)cnts)[tid + k * 64] = 0;
  if (tid < NEXP) lcnt[tid] = 0;
  __syncthreads();
#pragma unroll
  for (int k = 0; k < 2; ++k) {
    int ch = tid * 2 + k;
    const unsigned* p = tokE + ch * 64;
#pragma unroll 8
    for (int i = 0; i < 64; ++i) {
      unsigned v = p[i];
      atomicAdd(&cnts[ch][v & 255], 1);
      atomicAdd(&cnts[ch][(v >> 8) & 255], 1);
    }
  }
  __syncthreads();
  if (tid < NEXP) {
    int run = 0, base = 0;
    for (int q = 0; q < NCHUNK; ++q) {
      if (q == c) base = run;
      run += cnts[q][tid];
    }
    base8[tid] = base;
    if (c == 0) ctrl[tid] = run;
  }
  __syncthreads();
  int t = c * 64 + tid;
  unsigned v = tokE[t];
  int e0 = v & 255, e1 = (v >> 8) & 255;
  float2 w = tokW2[t];
  int l0 = atomicAdd(&lcnt[e0], 1);
  int l1 = atomicAdd(&lcnt[e1], 1);
  int i0 = base8[e0] + l0;
  int i1 = base8[e1] + l1;
  listTok[e0 * LSTRIDE + i0] = t; listW[e0 * LSTRIDE + i0] = w.x; listSlot[e0 * LSTRIDE + i0] = 0;
  listTok[e1 * LSTRIDE + i1] = t; listW[e1 * LSTRIDE + i1] = w.y; listSlot[e1 * LSTRIDE + i1] = 1;
}

// =====================================================================
// GEMM1: h = silu(Xg @ Wg^T) * (Xg @ Wi^T)   [8-phase; K-loop fully
// unrolled so all staging offsets fold into load immediates]
// blockIdx.z==8 -> 512 role-split blocks convert wout (fp32->bf16).
// =====================================================================
__global__ __launch_bounds__(512, 2) void k_gemm1(const unsigned short* __restrict__ xbf,
    const unsigned short* __restrict__ wg, const unsigned short* __restrict__ wi,
    const int* __restrict__ ctrl, const int* __restrict__ listTok,
    unsigned short* __restrict__ hbuf,
    const float* __restrict__ wout, unsigned short* __restrict__ wob) {
  int e = blockIdx.z;
  if (e == 8) {
    int g = (blockIdx.x + blockIdx.y * 16) * 512 + threadIdx.x;
    const int stride = 512 * 512;
#pragma unroll
    for (int it = 0; it < 8; ++it) {
      const f32x4* s = (const f32x4*)(wout + (size_t)g * 8);
      f32x4 a = s[0], c = s[1];
      s16x8 o;
      o[0] = f2bf(a[0]); o[1] = f2bf(a[1]); o[2] = f2bf(a[2]); o[3] = f2bf(a[3]);
      o[4] = f2bf(c[0]); o[5] = f2bf(c[1]); o[6] = f2bf(c[2]); o[7] = f2bf(c[3]);
      *(s16x8*)(wob + (size_t)g * 8) = o;
      g += stride;
    }
    return;
  }
  int cnt = ctrl[e];
  int m0 = blockIdx.y * 256;
  if (m0 >= cnt) return;
  int rowb = rowbase(ctrl, e);
  int n0 = blockIdx.x * 128;

  __shared__ __align__(16) char lds[131072];
  char* ldsc = &lds[0];

  int tid = threadIdx.x, lane = tid & 63, wv = tid >> 6;
  int wm = wv >> 1, wn = wv & 1;

  int srow = tid >> 3;
  int scol = (((tid & 7) ^ ((tid >> 3) & 7)) << 4);  // inverse-swizzled source col byte
  int sdst = wv << 10;                               // wave-uniform LDS dest
  const char* pA[2][2];
  const char* pBg[2];
  const char* pBi[2];
#pragma unroll
  for (int rg = 0; rg < 2; ++rg)
#pragma unroll
    for (int sb = 0; sb < 2; ++sb) {
      int idx = m0 + rg * 128 + sb * 64 + srow;
      if (idx >= cnt) idx = cnt - 1;                 // pad rows: clamp (cnt>=1 here)
      int tok = listTok[e * LSTRIDE + idx];
      pA[rg][sb] = (const char*)xbf + (size_t)tok * 2048 + scol;
    }
#pragma unroll
  for (int sb = 0; sb < 2; ++sb) {
    pBg[sb] = (const char*)wg + ((size_t)e * HDIM + n0 + sb * 64 + srow) * 2048 + scol;
    pBi[sb] = (const char*)wi + ((size_t)e * HDIM + n0 + sb * 64 + srow) * 2048 + scol;
  }

  int rowB = (lane & 15) << 7;
  int mk = (lane & 7) << 4;
  int q16 = (lane >> 4) << 4;
  int c0 = q16 ^ mk, c1 = (q16 + 64) ^ mk;
  int aO0 = 32768 + (wm >> 1) * 16384 + ((wm & 1) * 64) * 128 + rowB + c0;
  int aO1 = aO0 - c0 + c1;
  int gO0 = (wn * 64) * 128 + rowB + c0;
  int gO1 = gO0 - c0 + c1;
  int iO0 = 16384 + (wn * 64) * 128 + rowB + c0;
  int iO1 = iO0 - c0 + c1;

#define G1_STA(BUF, RG, KO) do { \
    gll16(pA[RG][0] + (KO), ldsc + (BUF) + 32768 + (RG) * 16384 + sdst); \
    gll16(pA[RG][1] + (KO), ldsc + (BUF) + 32768 + (RG) * 16384 + 8192 + sdst); } while (0)
#define G1_STG(BUF, KO) do { \
    gll16(pBg[0] + (KO), ldsc + (BUF) + sdst); \
    gll16(pBg[1] + (KO), ldsc + (BUF) + 8192 + sdst); } while (0)
#define G1_STI(BUF, KO) do { \
    gll16(pBi[0] + (KO), ldsc + (BUF) + 16384 + sdst); \
    gll16(pBi[1] + (KO), ldsc + (BUF) + 16384 + 8192 + sdst); } while (0)
#define G1_RDA(BUF) { _Pragma("unroll") for (int mf = 0; mf < 4; ++mf) { \
    af[mf][0] = *(const s16x8*)(ldsc + (BUF) + aO0 + mf * 2048); \
    af[mf][1] = *(const s16x8*)(ldsc + (BUF) + aO1 + mf * 2048); } }
#define G1_RDG(BUF) { _Pragma("unroll") for (int nf = 0; nf < 4; ++nf) { \
    bg[nf][0] = *(const s16x8*)(ldsc + (BUF) + gO0 + nf * 2048); \
    bg[nf][1] = *(const s16x8*)(ldsc + (BUF) + gO1 + nf * 2048); } }
#define G1_RDI(BUF) { _Pragma("unroll") for (int nf = 0; nf < 4; ++nf) { \
    bi[nf][0] = *(const s16x8*)(ldsc + (BUF) + iO0 + nf * 2048); \
    bi[nf][1] = *(const s16x8*)(ldsc + (BUF) + iO1 + nf * 2048); } }
#define G1_MMG(NH) do { __builtin_amdgcn_s_setprio(1); \
    _Pragma("unroll") for (int mf = 0; mf < 4; ++mf) _Pragma("unroll") for (int nf = 0; nf < 2; ++nf) { \
      accg[mf][(NH)*2+nf] = __builtin_amdgcn_mfma_f32_16x16x32_bf16(af[mf][0], bg[(NH)*2+nf][0], accg[mf][(NH)*2+nf], 0, 0, 0); \
      accg[mf][(NH)*2+nf] = __builtin_amdgcn_mfma_f32_16x16x32_bf16(af[mf][1], bg[(NH)*2+nf][1], accg[mf][(NH)*2+nf], 0, 0, 0); } \
    __builtin_amdgcn_s_setprio(0); } while (0)
#define G1_MMI(NH) do { __builtin_amdgcn_s_setprio(1); \
    _Pragma("unroll") for (int mf = 0; mf < 4; ++mf) _Pragma("unroll") for (int nf = 0; nf < 2; ++nf) { \
      acci[mf][(NH)*2+nf] = __builtin_amdgcn_mfma_f32_16x16x32_bf16(af[mf][0], bi[(NH)*2+nf][0], acci[mf][(NH)*2+nf], 0, 0, 0); \
      acci[mf][(NH)*2+nf] = __builtin_amdgcn_mfma_f32_16x16x32_bf16(af[mf][1], bi[(NH)*2+nf][1], acci[mf][(NH)*2+nf], 0, 0, 0); } \
    __builtin_amdgcn_s_setprio(0); } while (0)

  f32x4 accg[4][4], acci[4][4];
#pragma unroll
  for (int a = 0; a < 4; ++a)
#pragma unroll
    for (int b = 0; b < 4; ++b) { accg[a][b] = (f32x4){0.f,0.f,0.f,0.f}; acci[a][b] = (f32x4){0.f,0.f,0.f,0.f}; }
  s16x8 af[4][2], bg[4][2], bi[4][2];

  G1_STG(0, 0); G1_STA(0, 0, 0); G1_STI(0, 0); G1_STA(0, 1, 0);
  G1_STG(65536, 128); G1_STA(65536, 0, 128); G1_STI(65536, 128);
  VMW6();
  BAR_END();

  const int NIT = DDIM / 128;
#pragma unroll
  for (int i = 0; i < NIT; ++i) {
    const int koC = (2 * i + 1) * 128, koA = (2 * i + 2) * 128, koB = (2 * i + 3) * 128;
    const bool more = (i + 1 < NIT);
    G1_RDA(0); G1_RDG(0);
    G1_STA(65536, 1, koC);
    BAR_MID();
    G1_MMG(0);
    BAR_END();
    if (more) G1_STG(0, koA);
    BAR_MID();
    G1_MMG(1);
    BAR_END();
    G1_RDI(0);
    if (more) G1_STA(0, 0, koA);
    BAR_MID();
    G1_MMI(0);
    BAR_END();
    if (more) G1_STI(0, koA);
    BAR_MID();
    G1_MMI(1);
    if (more) VMW6(); else VMW0();
    BAR_END();
    G1_RDA(65536); G1_RDG(65536);
    if (more) G1_STA(0, 1, koA);
    BAR_MID();
    G1_MMG(0);
    BAR_END();
    if (more) G1_STG(65536, koB);
    BAR_MID();
    G1_MMG(1);
    BAR_END();
    G1_RDI(65536);
    if (more) G1_STA(65536, 0, koB);
    BAR_MID();
    G1_MMI(0);
    BAR_END();
    if (more) G1_STI(65536, koB);
    BAR_MID();
    G1_MMI(1);
    if (more) VMW6();
    BAR_END();
  }

#pragma unroll
  for (int mf = 0; mf < 4; ++mf)
#pragma unroll
    for (int j = 0; j < 4; ++j) {
      int r = wm * 64 + mf * 16 + ((lane >> 4) << 2) + j;
      size_t rowoff = (size_t)(rowb + m0 + r) * HDIM;
#pragma unroll
      for (int nf = 0; nf < 4; ++nf) {
        int cc = n0 + wn * 64 + nf * 16 + (lane & 15);
        float g = accg[mf][nf][j];
        float iv = acci[mf][nf][j];
        float hv = g / (1.f + __expf(-g)) * iv;
        hbuf[rowoff + cc] = f2bf(hv);
      }
    }
#undef G1_STA
#undef G1_STG
#undef G1_STI
#undef G1_RDA
#undef G1_RDG
#undef G1_RDI
#undef G1_MMG
#undef G1_MMI
}

// =====================================================================
// GEMM2: y[slot][token] = w * (h @ Wo^T)
// 4-phase, BM=256, BN=128, BK=64, 8 waves (4M x 2N), 16x16x32 MFMA.
// K-loop fully unrolled (staging offsets fold into load immediates).
// =====================================================================
__global__ __launch_bounds__(512, 2) void k_gemm2(const unsigned short* __restrict__ hbuf,
    const unsigned short* __restrict__ wo, const int* __restrict__ ctrl,
    const int* __restrict__ listTok, const float* __restrict__ listW,
    const int* __restrict__ listSlot, unsigned short* __restrict__ ybuf) {
  int e = blockIdx.z;
  int cnt = ctrl[e];
  int m0 = blockIdx.y * 256;
  if (m0 >= cnt) return;
  int rowb = rowbase(ctrl, e);
  int n0 = blockIdx.x * 128;

  __shared__ __align__(16) char lds[98304];
  char* ldsc = &lds[0];
#define BUF2 49152

  int tid = threadIdx.x, lane = tid & 63, wv = tid >> 6;
  int wm = wv >> 1, wn = wv & 1;

  int srow = tid >> 3;
  int scol = (((tid & 7) ^ ((tid >> 3) & 7)) << 4);
  int sdst = wv << 10;
  const char* pA[2][2];
  const char* pB[2];
#pragma unroll
  for (int rg = 0; rg < 2; ++rg)
#pragma unroll
    for (int sb = 0; sb < 2; ++sb)
      pA[rg][sb] = (const char*)hbuf + (size_t)(rowb + m0 + rg * 128 + sb * 64 + srow) * 4096 + scol;
#pragma unroll
  for (int sb = 0; sb < 2; ++sb)
    pB[sb] = (const char*)wo + ((size_t)e * DDIM + n0 + sb * 64 + srow) * 4096 + scol;

  int rowB = (lane & 15) << 7;
  int mk = (lane & 7) << 4;
  int q16 = (lane >> 4) << 4;
  int c0 = q16 ^ mk, c1 = (q16 + 64) ^ mk;
  int aO0 = wm * 8192 + rowB + c0;
  int aO1 = aO0 - c0 + c1;
  int bO0 = 32768 + wn * 8192 + rowB + c0;
  int bO1 = bO0 - c0 + c1;

#define G2_STA(BUF, RG, KO) do { \
    gll16(pA[RG][0] + (KO), ldsc + (BUF) + (RG) * 16384 + sdst); \
    gll16(pA[RG][1] + (KO), ldsc + (BUF) + (RG) * 16384 + 8192 + sdst); } while (0)
#define G2_STB(BUF, KO) do { \
    gll16(pB[0] + (KO), ldsc + (BUF) + 32768 + sdst); \
    gll16(pB[1] + (KO), ldsc + (BUF) + 32768 + 8192 + sdst); } while (0)
#define G2_RDA(BUF) { _Pragma("unroll") for (int mf = 0; mf < 4; ++mf) { \
    af[mf][0] = *(const s16x8*)(ldsc + (BUF) + aO0 + mf * 2048); \
    af[mf][1] = *(const s16x8*)(ldsc + (BUF) + aO1 + mf * 2048); } }
#define G2_RDB(BUF) { _Pragma("unroll") for (int nf = 0; nf < 4; ++nf) { \
    bf[nf][0] = *(const s16x8*)(ldsc + (BUF) + bO0 + nf * 2048); \
    bf[nf][1] = *(const s16x8*)(ldsc + (BUF) + bO1 + nf * 2048); } }
#define G2_MM(NH) do { __builtin_amdgcn_s_setprio(1); \
    _Pragma("unroll") for (int mf = 0; mf < 4; ++mf) _Pragma("unroll") for (int nf = 0; nf < 2; ++nf) { \
      acc[mf][(NH)*2+nf] = __builtin_amdgcn_mfma_f32_16x16x32_bf16(af[mf][0], bf[(NH)*2+nf][0], acc[mf][(NH)*2+nf], 0, 0, 0); \
      acc[mf][(NH)*2+nf] = __builtin_amdgcn_mfma_f32_16x16x32_bf16(af[mf][1], bf[(NH)*2+nf][1], acc[mf][(NH)*2+nf], 0, 0, 0); } \
    __builtin_amdgcn_s_setprio(0); } while (0)

  f32x4 acc[4][4];
#pragma unroll
  for (int a = 0; a < 4; ++a)
#pragma unroll
    for (int b = 0; b < 4; ++b) acc[a][b] = (f32x4){0.f,0.f,0.f,0.f};
  s16x8 af[4][2], bf[4][2];

  G2_STA(0, 0, 0); G2_STA(0, 1, 0); G2_STB(0, 0);
  G2_STA(BUF2, 0, 128); G2_STA(BUF2, 1, 128); G2_STB(BUF2, 128);
  VMW6();
  BAR_END();

  const int NIT = HDIM / 128;
#pragma unroll
  for (int i = 0; i < NIT; ++i) {
    const int koA = (2 * i + 2) * 128, koB = (2 * i + 3) * 128;
    const bool more = (i + 1 < NIT);
    G2_RDA(0); G2_RDB(0);
    BAR_MID();
    G2_MM(0);
    BAR_END();
    if (more) { G2_STA(0, 0, koA); G2_STA(0, 1, koA); G2_STB(0, koA); }
    BAR_MID();
    G2_MM(1);
    if (more) VMW6(); else VMW0();
    BAR_END();
    G2_RDA(BUF2); G2_RDB(BUF2);
    BAR_MID();
    G2_MM(0);
    BAR_END();
    if (more) { G2_STA(BUF2, 0, koB); G2_STA(BUF2, 1, koB); G2_STB(BUF2, koB); }
    BAR_MID();
    G2_MM(1);
    VMW6();
    BAR_END();
  }

#pragma unroll
  for (int mf = 0; mf < 4; ++mf)
#pragma unroll
    for (int j = 0; j < 4; ++j) {
      int r = wm * 64 + mf * 16 + ((lane >> 4) << 2) + j;
      int mrow = m0 + r;
      if (mrow < cnt) {
        int tok = listTok[e * LSTRIDE + mrow];
        float wgt = listW[e * LSTRIDE + mrow];
        int slot = listSlot[e * LSTRIDE + mrow];
        size_t base = ((size_t)slot * NTOK + tok) * DDIM + n0 + wn * 64;
#pragma unroll
        for (int nf = 0; nf < 4; ++nf)
          ybuf[base + nf * 16 + (lane & 15)] = f2bf(acc[mf][nf][j] * wgt);
      }
    }
#undef G2_STA
#undef G2_STB
#undef G2_RDA
#undef G2_RDB
#undef G2_MM
#undef BUF2
}

// ---- reduce: out = y0 + y1 (fp32 out), vectorized ----
__global__ __launch_bounds__(256) void k_reduce(const unsigned short* __restrict__ ybuf,
                                                float* __restrict__ out, int n8) {
  int i = blockIdx.x * blockDim.x + threadIdx.x;
  int stride = gridDim.x * blockDim.x;
  const unsigned short* y0 = ybuf;
  const unsigned short* y1 = ybuf + (size_t)NTOK * DDIM;
  for (; i < n8; i += stride) {
    s16x8 a = *(const s16x8*)(y0 + (size_t)i * 8);
    s16x8 b = *(const s16x8*)(y1 + (size_t)i * 8);
    f32x4 o0, o1;
#pragma unroll
    for (int j = 0; j < 4; ++j) o0[j] = bf2f((unsigned short)a[j]) + bf2f((unsigned short)b[j]);
#pragma unroll
    for (int j = 0; j < 4; ++j) o1[j] = bf2f((unsigned short)a[4 + j]) + bf2f((unsigned short)b[4 + j]);
    f32x4* d = (f32x4*)(out + (size_t)i * 8);
    d[0] = o0; d[1] = o1;
  }
}

extern "C" void kernel_launch(void* const* d_in, const int* in_sizes, int n_in,
                              void* d_out, int out_size, void* d_ws, size_t ws_size,
                              hipStream_t stream) {
  const float* x     = (const float*)d_in[0];
  const float* gw    = (const float*)d_in[1];
  const float* wgate = (const float*)d_in[2];
  const float* win   = (const float*)d_in[3];
  const float* wout  = (const float*)d_in[4];
  float* out = (float*)d_out;

  const size_t LBYTES     = (size_t)NEXP * LSTRIDE * 4;
  const size_t OFF_LIST   = 256;
  const size_t OFF_LISTW  = OFF_LIST + LBYTES;
  const size_t OFF_SLOT   = OFF_LISTW + LBYTES;
  const size_t OFF_TE     = OFF_SLOT + LBYTES;          // tokE: NTOK u32
  const size_t OFF_TW     = OFF_TE + (size_t)NTOK * 4;  // tokW2: NTOK float2
  const size_t OFF_XBF = (size_t)1 << 20;
  const size_t OFF_WG  = OFF_XBF + (size_t)NTOK * DDIM * 2;
  const size_t OFF_WI  = OFF_WG + (size_t)NEXP * HDIM * DDIM * 2;
  const size_t OFF_WO  = OFF_WI + (size_t)NEXP * HDIM * DDIM * 2;
  const size_t OFF_H   = OFF_WO + (size_t)NEXP * DDIM * HDIM * 2;
  const size_t OFF_Y   = OFF_WG;                        // ybuf aliases wgb (dead after gemm1)
  const size_t TOTAL   = OFF_H + (size_t)MAXROWS * HDIM * 2;

  if (ws_size < TOTAL) { k_sentinel<<<1, 64, 0, stream>>>(out); return; }

  char* ws = (char*)d_ws;
  int* ctrl            = (int*)ws;                      // [0..7]=cnt
  int* listTok         = (int*)(ws + OFF_LIST);
  float* listW         = (float*)(ws + OFF_LISTW);
  int* listSlot        = (int*)(ws + OFF_SLOT);
  unsigned* tokE       = (unsigned*)(ws + OFF_TE);
  float2* tokW2        = (float2*)(ws + OFF_TW);
  unsigned short* xbf  = (unsigned short*)(ws + OFF_XBF);
  unsigned short* wgb  = (unsigned short*)(ws + OFF_WG);
  unsigned short* wib  = (unsigned short*)(ws + OFF_WI);
  unsigned short* wob  = (unsigned short*)(ws + OFF_WO);
  unsigned short* hbuf = (unsigned short*)(ws + OFF_H);
  unsigned short* ybuf = (unsigned short*)(ws + OFF_Y);

  k_prep<<<3072, 256, 0, stream>>>(x, gw, wgate, win, wgb, wib, tokE, tokW2, xbf);
  k_sort<<<NCHUNK, 64, 0, stream>>>(tokE, tokW2, ctrl, listTok, listW, listSlot);

  k_gemm1<<<dim3(HDIM / 128, NTOK / 256, NEXP + 1), 512, 0, stream>>>(xbf, wgb, wib, ctrl, listTok, hbuf, wout, wob);
  k_gemm2<<<dim3(DDIM / 128, NTOK / 256, NEXP), 512, 0, stream>>>(hbuf, wob, ctrl, listTok, listW, listSlot, ybuf);
  k_reduce<<<512, 256, 0, stream>>>(ybuf, out, NTOK * DDIM / 8);
}